// Round 1
// baseline (2372.990 us; speedup 1.0000x reference)
//
#include <hip/hip_runtime.h>

#define NN 50000
#define EE 800000
#define ETOT 850000
#define FIN 256
#define F1 128
#define F2 40

// ---------------- GEMM1: h1[N,128] = x[N,256] @ W1[256,128] ----------------
__global__ __launch_bounds__(256) void gemm1_kernel(const float* __restrict__ x,
                                                    const float* __restrict__ W1,
                                                    float* __restrict__ h1) {
  __shared__ float Alds[16 * 68];    // [k][row], pad 64->68 to break store conflicts
  __shared__ float Blds[16 * 128];   // [k][col]
  const int t = threadIdx.x;
  const int tx = t & 15;             // col group: cols tx*4..+3 and tx*4+64..+67
  const int ty = t >> 4;             // row group: rows ty*4..+3
  const int m0 = blockIdx.x * 64;
  const int arow = t >> 2;           // 0..63
  const int akk = (t & 3) * 4;       // 0..12
  const int brow = t >> 4;           // 0..15
  const int bc = (t & 15) * 4;       // 0..60

  float acc[4][8];
#pragma unroll
  for (int i = 0; i < 4; ++i)
#pragma unroll
    for (int j = 0; j < 8; ++j) acc[i][j] = 0.f;

  for (int k0 = 0; k0 < FIN; k0 += 16) {
    float4 av = {0.f, 0.f, 0.f, 0.f};
    int gr = m0 + arow;
    if (gr < NN) av = *(const float4*)(x + (size_t)gr * FIN + k0 + akk);
    float4 bv0 = *(const float4*)(W1 + (size_t)(k0 + brow) * F1 + bc);
    float4 bv1 = *(const float4*)(W1 + (size_t)(k0 + brow) * F1 + bc + 64);
    __syncthreads();
    Alds[(akk + 0) * 68 + arow] = av.x;
    Alds[(akk + 1) * 68 + arow] = av.y;
    Alds[(akk + 2) * 68 + arow] = av.z;
    Alds[(akk + 3) * 68 + arow] = av.w;
    *(float4*)(Blds + brow * 128 + bc) = bv0;
    *(float4*)(Blds + brow * 128 + bc + 64) = bv1;
    __syncthreads();
#pragma unroll
    for (int k = 0; k < 16; ++k) {
      float4 a4 = *(const float4*)(Alds + k * 68 + ty * 4);
      float4 b0 = *(const float4*)(Blds + k * 128 + tx * 4);
      float4 b1 = *(const float4*)(Blds + k * 128 + tx * 4 + 64);
      float aa[4] = {a4.x, a4.y, a4.z, a4.w};
      float bb[8] = {b0.x, b0.y, b0.z, b0.w, b1.x, b1.y, b1.z, b1.w};
#pragma unroll
      for (int i = 0; i < 4; ++i)
#pragma unroll
        for (int j = 0; j < 8; ++j) acc[i][j] = fmaf(aa[i], bb[j], acc[i][j]);
    }
  }
#pragma unroll
  for (int i = 0; i < 4; ++i) {
    int gr = m0 + ty * 4 + i;
    if (gr < NN) {
      float4 o0 = {acc[i][0], acc[i][1], acc[i][2], acc[i][3]};
      float4 o1 = {acc[i][4], acc[i][5], acc[i][6], acc[i][7]};
      *(float4*)(h1 + (size_t)gr * F1 + tx * 4) = o0;
      *(float4*)(h1 + (size_t)gr * F1 + tx * 4 + 64) = o1;
    }
  }
}

// ---------------- attention dots layer1: a_src/a_dst [N,4] ----------------
__global__ __launch_bounds__(256) void a1_kernel(const float* __restrict__ h1,
                                                 const float* __restrict__ att_src,
                                                 const float* __restrict__ att_dst,
                                                 float* __restrict__ a_src,
                                                 float* __restrict__ a_dst) {
  __shared__ float ss[128], sd[128];
  int t = threadIdx.x;
  if (t < 128) { ss[t] = att_src[t]; sd[t] = att_dst[t]; }
  __syncthreads();
  int n = blockIdx.x * 64 + (t >> 2);
  int h = t & 3;
  if (n >= NN) return;
  const float* row = h1 + (size_t)n * F1 + h * 32;
  const float* as = ss + h * 32;
  const float* ad = sd + h * 32;
  float accs = 0.f, accd = 0.f;
#pragma unroll
  for (int c = 0; c < 32; c += 4) {
    float4 v = *(const float4*)(row + c);
    accs += v.x * as[c] + v.y * as[c + 1] + v.z * as[c + 2] + v.w * as[c + 3];
    accd += v.x * ad[c] + v.y * ad[c + 1] + v.z * ad[c + 2] + v.w * ad[c + 3];
  }
  a_src[n * 4 + h] = accs;
  a_dst[n * 4 + h] = accd;
}

// ---------------- edge pass 1: agg1[dst] += exp(e)*h1[src], s1[dst] += exp(e) --------
__global__ __launch_bounds__(256) void edge1_kernel(const int* __restrict__ ei,
                                                    const float* __restrict__ a_src,
                                                    const float* __restrict__ a_dst,
                                                    const float* __restrict__ h1,
                                                    float* __restrict__ agg1,
                                                    float* __restrict__ s1) {
  int t = threadIdx.x;
  int e = blockIdx.x * 8 + (t >> 5);     // 32 lanes per edge
  if (e >= ETOT) return;
  int l = t & 31;
  int src, dst;
  if (e < EE) { src = ei[e]; dst = ei[EE + e]; }
  else        { src = e - EE; dst = src; }
  int head = l >> 3;
  float a = a_src[src * 4 + head] + a_dst[dst * 4 + head];
  a = a > 0.f ? a : 0.2f * a;
  float ex = __expf(a);
  int f0 = l * 4;
  float4 hv = *(const float4*)(h1 + (size_t)src * F1 + f0);
  float* dp = agg1 + (size_t)dst * F1 + f0;
  atomicAdd(dp + 0, ex * hv.x);
  atomicAdd(dp + 1, ex * hv.y);
  atomicAdd(dp + 2, ex * hv.z);
  atomicAdd(dp + 3, ex * hv.w);
  if ((l & 7) == 0) atomicAdd(s1 + dst * 4 + head, ex);
}

// ---------- divide + bias, in-place; accumulate BN sum/sumsq per feature ----------
__global__ __launch_bounds__(256) void bnpre_kernel(float* __restrict__ agg1,
                                                    const float* __restrict__ s1,
                                                    const float* __restrict__ b1,
                                                    float* __restrict__ bnsum,
                                                    float* __restrict__ bnsq) {
  __shared__ float red[256];
  int t = threadIdx.x;
  int f = t & 127;
  int rl = t >> 7;
  int n0 = blockIdx.x * 64;
  float bias = b1[f];
  float sum = 0.f, sq = 0.f;
  for (int i = 0; i < 64; i += 2) {
    int n = n0 + i + rl;
    if (n < NN) {
      float inv = 1.f / (s1[n * 4 + (f >> 5)] + 1e-16f);
      float v = agg1[(size_t)n * F1 + f] * inv + bias;
      agg1[(size_t)n * F1 + f] = v;
      sum += v;
      sq += v * v;
    }
  }
  red[t] = sum;
  __syncthreads();
  if (t < 128) atomicAdd(bnsum + f, sum + red[t + 128]);
  __syncthreads();
  red[t] = sq;
  __syncthreads();
  if (t < 128) atomicAdd(bnsq + f, sq + red[t + 128]);
}

// ---------------- BN stats -> per-feature scale/shift ----------------
__global__ void bnstats_kernel(const float* __restrict__ bnsum, const float* __restrict__ bnsq,
                               const float* __restrict__ gamma, const float* __restrict__ beta,
                               float* __restrict__ scale, float* __restrict__ shift) {
  int f = threadIdx.x;
  if (f < 128) {
    const float invN = 1.f / (float)NN;
    float mu = bnsum[f] * invN;
    float var = bnsq[f] * invN - mu * mu;
    float sc = gamma[f] * rsqrtf(var + 1e-5f);
    scale[f] = sc;
    shift[f] = beta[f] - mu * sc;
  }
}

// -------- GEMM2 (BN+ELU fused on A-load): h2[N,40] = elu(bn(hpre)) @ W2[128,40] -----
__global__ __launch_bounds__(256) void gemm2_kernel(const float* __restrict__ hpre,
                                                    const float* __restrict__ W2,
                                                    const float* __restrict__ scale,
                                                    const float* __restrict__ shift,
                                                    float* __restrict__ h2) {
  __shared__ float Wlds[128 * 40];
  __shared__ float Alds[16 * 128];   // [k][row]
  __shared__ float sc[128], sh[128];
  int t = threadIdx.x;
  for (int i = t; i < 128 * 40; i += 256) Wlds[i] = W2[i];
  if (t < 128) { sc[t] = scale[t]; sh[t] = shift[t]; }
  int tr = t >> 3;       // 0..31 -> rows tr*4..+3
  int tc = t & 7;        // cols tc*5..+4
  int n0 = blockIdx.x * 128;
  int lrow = t >> 1;     // 0..127
  int lkk = (t & 1) * 8; // 0 or 8
  float acc[4][5];
#pragma unroll
  for (int i = 0; i < 4; ++i)
#pragma unroll
    for (int j = 0; j < 5; ++j) acc[i][j] = 0.f;

  for (int k0 = 0; k0 < F1; k0 += 16) {
    float av[8];
    int gn = n0 + lrow;
    if (gn < NN) {
      float4 v0 = *(const float4*)(hpre + (size_t)gn * F1 + k0 + lkk);
      float4 v1 = *(const float4*)(hpre + (size_t)gn * F1 + k0 + lkk + 4);
      av[0] = v0.x; av[1] = v0.y; av[2] = v0.z; av[3] = v0.w;
      av[4] = v1.x; av[5] = v1.y; av[6] = v1.z; av[7] = v1.w;
    } else {
#pragma unroll
      for (int j = 0; j < 8; ++j) av[j] = 0.f;
    }
    __syncthreads();
#pragma unroll
    for (int j = 0; j < 8; ++j) {
      int kg = k0 + lkk + j;
      float a = av[j] * sc[kg] + sh[kg];
      a = a > 0.f ? a : (__expf(a) - 1.f);   // ELU
      Alds[(lkk + j) * 128 + lrow] = a;
    }
    __syncthreads();
#pragma unroll
    for (int k = 0; k < 16; ++k) {
      float4 a4 = *(const float4*)(Alds + k * 128 + tr * 4);
      float aa[4] = {a4.x, a4.y, a4.z, a4.w};
      float w[5];
#pragma unroll
      for (int j = 0; j < 5; ++j) w[j] = Wlds[(k0 + k) * 40 + tc * 5 + j];
#pragma unroll
      for (int i = 0; i < 4; ++i)
#pragma unroll
        for (int j = 0; j < 5; ++j) acc[i][j] = fmaf(aa[i], w[j], acc[i][j]);
    }
  }
#pragma unroll
  for (int i = 0; i < 4; ++i) {
    int gn = n0 + tr * 4 + i;
    if (gn < NN) {
#pragma unroll
      for (int j = 0; j < 5; ++j) h2[(size_t)gn * F2 + tc * 5 + j] = acc[i][j];
    }
  }
}

// ---------------- attention dots layer2 ----------------
__global__ __launch_bounds__(256) void a2_kernel(const float* __restrict__ h2,
                                                 const float* __restrict__ att_src2,
                                                 const float* __restrict__ att_dst2,
                                                 float* __restrict__ a_src2,
                                                 float* __restrict__ a_dst2) {
  __shared__ float ss[40], sd[40];
  int t = threadIdx.x;
  if (t < 40) { ss[t] = att_src2[t]; sd[t] = att_dst2[t]; }
  __syncthreads();
  int n = blockIdx.x * 256 + t;
  if (n >= NN) return;
  const float* row = h2 + (size_t)n * F2;
  float as = 0.f, ad = 0.f;
#pragma unroll
  for (int c = 0; c < 40; ++c) {
    float v = row[c];
    as += v * ss[c];
    ad += v * sd[c];
  }
  a_src2[n] = as;
  a_dst2[n] = ad;
}

// ---------------- edge pass 2 ----------------
__global__ __launch_bounds__(256) void edge2_kernel(const int* __restrict__ ei,
                                                    const float* __restrict__ a_src,
                                                    const float* __restrict__ a_dst,
                                                    const float* __restrict__ h2,
                                                    float* __restrict__ agg2,
                                                    float* __restrict__ s2) {
  int t = threadIdx.x;
  int e = blockIdx.x * 32 + (t >> 3);   // 8 lanes per edge
  if (e >= ETOT) return;
  int l = t & 7;
  int src, dst;
  if (e < EE) { src = ei[e]; dst = ei[EE + e]; }
  else        { src = e - EE; dst = src; }
  float a = a_src[src] + a_dst[dst];
  a = a > 0.f ? a : 0.2f * a;
  float ex = __expf(a);
  int f0 = l * 5;
  const float* hp = h2 + (size_t)src * F2 + f0;
  float* dp = agg2 + (size_t)dst * F2 + f0;
#pragma unroll
  for (int j = 0; j < 5; ++j) atomicAdd(dp + j, ex * hp[j]);
  if (l == 0) atomicAdd(s2 + dst, ex);
}

// ---------------- final: out = agg2/s2 + b2 ----------------
__global__ __launch_bounds__(256) void out_kernel(const float* __restrict__ agg2,
                                                  const float* __restrict__ s2,
                                                  const float* __restrict__ b2,
                                                  float* __restrict__ out) {
  int i = blockIdx.x * 256 + threadIdx.x;
  if (i >= NN * F2) return;
  int n = i / F2;
  int c = i - n * F2;
  out[i] = agg2[i] / (s2[n] + 1e-16f) + b2[c];
}

extern "C" void kernel_launch(void* const* d_in, const int* in_sizes, int n_in,
                              void* d_out, int out_size, void* d_ws, size_t ws_size,
                              hipStream_t stream) {
  const float* x        = (const float*)d_in[0];
  const int*   ei       = (const int*)d_in[1];
  const float* W1       = (const float*)d_in[2];
  const float* att_src1 = (const float*)d_in[3];
  const float* att_dst1 = (const float*)d_in[4];
  const float* b1       = (const float*)d_in[5];
  const float* gamma    = (const float*)d_in[6];
  const float* beta     = (const float*)d_in[7];
  const float* W2       = (const float*)d_in[8];
  const float* att_src2 = (const float*)d_in[9];
  const float* att_dst2 = (const float*)d_in[10];
  const float* b2       = (const float*)d_in[11];
  float* out = (float*)d_out;
  float* ws  = (float*)d_ws;

  // ---- workspace layout (floats). Zeroed region first (single memset). ----
  float* agg1  = ws;                   // N*128 = 6,400,000
  float* s1    = agg1 + 6400000;       // N*4   =   200,000
  float* bnsum = s1 + 200000;          // 128
  float* bnsq  = bnsum + 128;          // 128
  float* agg2  = bnsq + 128;           // N*40  = 2,000,000
  float* s2    = agg2 + 2000000;       // N     =    50,000
  const size_t zero_floats = 6400000 + 200000 + 128 + 128 + 2000000 + 50000;
  float* h1     = s2 + 50000;          // N*128 (reused as h2 after layer1 done)
  float* h2     = h1;
  float* a_src1 = h1 + 6400000;        // N*4
  float* a_dst1 = a_src1 + 200000;     // N*4
  float* a_src2 = a_dst1 + 200000;     // N
  float* a_dst2 = a_src2 + 50000;      // N
  float* scale  = a_dst2 + 50000;      // 128
  float* shift  = scale + 128;         // 128

  hipMemsetAsync(agg1, 0, zero_floats * sizeof(float), stream);

  gemm1_kernel<<<(NN + 63) / 64, 256, 0, stream>>>(x, W1, h1);
  a1_kernel<<<(NN + 63) / 64, 256, 0, stream>>>(h1, att_src1, att_dst1, a_src1, a_dst1);
  edge1_kernel<<<(ETOT + 7) / 8, 256, 0, stream>>>(ei, a_src1, a_dst1, h1, agg1, s1);
  bnpre_kernel<<<(NN + 63) / 64, 256, 0, stream>>>(agg1, s1, b1, bnsum, bnsq);
  bnstats_kernel<<<1, 128, 0, stream>>>(bnsum, bnsq, gamma, beta, scale, shift);
  gemm2_kernel<<<(NN + 127) / 128, 256, 0, stream>>>(agg1, W2, scale, shift, h2);
  a2_kernel<<<(NN + 255) / 256, 256, 0, stream>>>(h2, att_src2, att_dst2, a_src2, a_dst2);
  edge2_kernel<<<(ETOT + 31) / 32, 256, 0, stream>>>(ei, a_src2, a_dst2, h2, agg2, s2);
  out_kernel<<<(NN * F2 + 255) / 256, 256, 0, stream>>>(agg2, s2, b2, out);
}

// Round 2
// 621.292 us; speedup vs baseline: 3.8194x; 3.8194x over previous
//
#include <hip/hip_runtime.h>

#define NN 50000
#define EE 800000
#define ETOT 850000
#define FIN 256
#define F1 128
#define F2 40

// ---------------- GEMM1: h1[N,128] = x[N,256] @ W1[256,128] ----------------
__global__ __launch_bounds__(256) void gemm1_kernel(const float* __restrict__ x,
                                                    const float* __restrict__ W1,
                                                    float* __restrict__ h1) {
  __shared__ float Alds[16 * 68];
  __shared__ float Blds[16 * 128];
  const int t = threadIdx.x;
  const int tx = t & 15;
  const int ty = t >> 4;
  const int m0 = blockIdx.x * 64;
  const int arow = t >> 2;
  const int akk = (t & 3) * 4;
  const int brow = t >> 4;
  const int bc = (t & 15) * 4;

  float acc[4][8];
#pragma unroll
  for (int i = 0; i < 4; ++i)
#pragma unroll
    for (int j = 0; j < 8; ++j) acc[i][j] = 0.f;

  for (int k0 = 0; k0 < FIN; k0 += 16) {
    float4 av = {0.f, 0.f, 0.f, 0.f};
    int gr = m0 + arow;
    if (gr < NN) av = *(const float4*)(x + (size_t)gr * FIN + k0 + akk);
    float4 bv0 = *(const float4*)(W1 + (size_t)(k0 + brow) * F1 + bc);
    float4 bv1 = *(const float4*)(W1 + (size_t)(k0 + brow) * F1 + bc + 64);
    __syncthreads();
    Alds[(akk + 0) * 68 + arow] = av.x;
    Alds[(akk + 1) * 68 + arow] = av.y;
    Alds[(akk + 2) * 68 + arow] = av.z;
    Alds[(akk + 3) * 68 + arow] = av.w;
    *(float4*)(Blds + brow * 128 + bc) = bv0;
    *(float4*)(Blds + brow * 128 + bc + 64) = bv1;
    __syncthreads();
#pragma unroll
    for (int k = 0; k < 16; ++k) {
      float4 a4 = *(const float4*)(Alds + k * 68 + ty * 4);
      float4 b0 = *(const float4*)(Blds + k * 128 + tx * 4);
      float4 b1 = *(const float4*)(Blds + k * 128 + tx * 4 + 64);
      float aa[4] = {a4.x, a4.y, a4.z, a4.w};
      float bb[8] = {b0.x, b0.y, b0.z, b0.w, b1.x, b1.y, b1.z, b1.w};
#pragma unroll
      for (int i = 0; i < 4; ++i)
#pragma unroll
        for (int j = 0; j < 8; ++j) acc[i][j] = fmaf(aa[i], bb[j], acc[i][j]);
    }
  }
#pragma unroll
  for (int i = 0; i < 4; ++i) {
    int gr = m0 + ty * 4 + i;
    if (gr < NN) {
      float4 o0 = {acc[i][0], acc[i][1], acc[i][2], acc[i][3]};
      float4 o1 = {acc[i][4], acc[i][5], acc[i][6], acc[i][7]};
      *(float4*)(h1 + (size_t)gr * F1 + tx * 4) = o0;
      *(float4*)(h1 + (size_t)gr * F1 + tx * 4 + 64) = o1;
    }
  }
}

// ---------------- attention dots layer1 ----------------
__global__ __launch_bounds__(256) void a1_kernel(const float* __restrict__ h1,
                                                 const float* __restrict__ att_src,
                                                 const float* __restrict__ att_dst,
                                                 float* __restrict__ a_src,
                                                 float* __restrict__ a_dst) {
  __shared__ float ss[128], sd[128];
  int t = threadIdx.x;
  if (t < 128) { ss[t] = att_src[t]; sd[t] = att_dst[t]; }
  __syncthreads();
  int n = blockIdx.x * 64 + (t >> 2);
  int h = t & 3;
  if (n >= NN) return;
  const float* row = h1 + (size_t)n * F1 + h * 32;
  const float* as = ss + h * 32;
  const float* ad = sd + h * 32;
  float accs = 0.f, accd = 0.f;
#pragma unroll
  for (int c = 0; c < 32; c += 4) {
    float4 v = *(const float4*)(row + c);
    accs += v.x * as[c] + v.y * as[c + 1] + v.z * as[c + 2] + v.w * as[c + 3];
    accd += v.x * ad[c] + v.y * ad[c + 1] + v.z * ad[c + 2] + v.w * ad[c + 3];
  }
  a_src[n * 4 + h] = accs;
  a_dst[n * 4 + h] = accd;
}

// ---------------- CSR build: degree histogram ----------------
__global__ __launch_bounds__(256) void deg_kernel(const int* __restrict__ ei,
                                                  int* __restrict__ deg) {
  int e = blockIdx.x * 256 + threadIdx.x;
  if (e >= ETOT) return;
  int dst = (e < EE) ? ei[EE + e] : (e - EE);
  atomicAdd(deg + dst, 1);
}

// ---------------- CSR build: exclusive scan (single block) ----------------
__global__ __launch_bounds__(1024) void scan_kernel(const int* __restrict__ deg,
                                                    int* __restrict__ rowstart,
                                                    int* __restrict__ cursor) {
  __shared__ int lds[1024];
  __shared__ int carry_s;
  int t = threadIdx.x;
  if (t == 0) carry_s = 0;
  __syncthreads();
  for (int base = 0; base < NN; base += 1024) {
    int idx = base + t;
    int v = (idx < NN) ? deg[idx] : 0;
    lds[t] = v;
    __syncthreads();
    for (int off = 1; off < 1024; off <<= 1) {
      int u = (t >= off) ? lds[t - off] : 0;
      __syncthreads();
      lds[t] += u;
      __syncthreads();
    }
    int excl = carry_s + lds[t] - v;
    int tot = lds[1023];
    if (idx < NN) { rowstart[idx] = excl; cursor[idx] = excl; }
    __syncthreads();
    if (t == 0) carry_s += tot;
    __syncthreads();
  }
  if (t == 0) rowstart[NN] = carry_s;
}

// ---------------- CSR build: scatter fill ----------------
__global__ __launch_bounds__(256) void fill_kernel(const int* __restrict__ ei,
                                                   int* __restrict__ cursor,
                                                   int* __restrict__ csr_src) {
  int e = blockIdx.x * 256 + threadIdx.x;
  if (e >= ETOT) return;
  int src, dst;
  if (e < EE) { src = ei[e]; dst = ei[EE + e]; }
  else        { src = e - EE; dst = src; }
  int pos = atomicAdd(cursor + dst, 1);
  csr_src[pos] = src;
}

// ------- gather layer1: pull aggregation, fused divide+bias+BN-stat -------
// 32 lanes per node; lane l: head=l>>3, feats l*4..l*4+3. 8 nodes per block.
__global__ __launch_bounds__(256) void gather1_kernel(const int* __restrict__ rowstart,
                                                      const int* __restrict__ csr_src,
                                                      const float* __restrict__ a_src,
                                                      const float* __restrict__ a_dst,
                                                      const float* __restrict__ h1,
                                                      const float* __restrict__ b1,
                                                      float* __restrict__ h1b,
                                                      float* __restrict__ bnsum,
                                                      float* __restrict__ bnsq) {
  __shared__ float bns[128], bnq[128];
  int t = threadIdx.x;
  if (t < 128) { bns[t] = 0.f; bnq[t] = 0.f; }
  __syncthreads();
  int n = blockIdx.x * 8 + (t >> 5);   // grid sized so n < NN always
  int l = t & 31;
  int head = l >> 3;
  int f0 = l * 4;
  float adst = a_dst[n * 4 + head];
  float acc0 = 0.f, acc1 = 0.f, acc2 = 0.f, acc3 = 0.f, ssum = 0.f;
  int beg = rowstart[n], end = rowstart[n + 1];
  int src = (beg < end) ? csr_src[beg] : 0;
  for (int i = beg; i < end; ++i) {
    int nsrc = (i + 1 < end) ? csr_src[i + 1] : 0;
    float e = a_src[src * 4 + head] + adst;
    e = e > 0.f ? e : 0.2f * e;
    float ex = __expf(e);
    float4 hv = *(const float4*)(h1 + (size_t)src * F1 + f0);
    acc0 = fmaf(ex, hv.x, acc0);
    acc1 = fmaf(ex, hv.y, acc1);
    acc2 = fmaf(ex, hv.z, acc2);
    acc3 = fmaf(ex, hv.w, acc3);
    ssum += ex;
    src = nsrc;
  }
  float inv = 1.f / (ssum + 1e-16f);
  float4 bb = *(const float4*)(b1 + f0);
  float4 o;
  o.x = acc0 * inv + bb.x;
  o.y = acc1 * inv + bb.y;
  o.z = acc2 * inv + bb.z;
  o.w = acc3 * inv + bb.w;
  *(float4*)(h1b + (size_t)n * F1 + f0) = o;
  atomicAdd(&bns[f0 + 0], o.x); atomicAdd(&bnq[f0 + 0], o.x * o.x);
  atomicAdd(&bns[f0 + 1], o.y); atomicAdd(&bnq[f0 + 1], o.y * o.y);
  atomicAdd(&bns[f0 + 2], o.z); atomicAdd(&bnq[f0 + 2], o.z * o.z);
  atomicAdd(&bns[f0 + 3], o.w); atomicAdd(&bnq[f0 + 3], o.w * o.w);
  __syncthreads();
  if (t < 128) {
    atomicAdd(bnsum + t, bns[t]);
    atomicAdd(bnsq + t, bnq[t]);
  }
}

// ---------------- BN stats -> per-feature scale/shift ----------------
__global__ void bnstats_kernel(const float* __restrict__ bnsum, const float* __restrict__ bnsq,
                               const float* __restrict__ gamma, const float* __restrict__ beta,
                               float* __restrict__ scale, float* __restrict__ shift) {
  int f = threadIdx.x;
  if (f < 128) {
    const float invN = 1.f / (float)NN;
    float mu = bnsum[f] * invN;
    float var = bnsq[f] * invN - mu * mu;
    float sc = gamma[f] * rsqrtf(var + 1e-5f);
    scale[f] = sc;
    shift[f] = beta[f] - mu * sc;
  }
}

// -------- GEMM2 (BN+ELU fused on A-load): h2[N,40] = elu(bn(h1b)) @ W2 -----
__global__ __launch_bounds__(256) void gemm2_kernel(const float* __restrict__ hpre,
                                                    const float* __restrict__ W2,
                                                    const float* __restrict__ scale,
                                                    const float* __restrict__ shift,
                                                    float* __restrict__ h2) {
  __shared__ float Wlds[128 * 40];
  __shared__ float Alds[16 * 128];
  __shared__ float sc[128], sh[128];
  int t = threadIdx.x;
  for (int i = t; i < 128 * 40; i += 256) Wlds[i] = W2[i];
  if (t < 128) { sc[t] = scale[t]; sh[t] = shift[t]; }
  int tr = t >> 3;
  int tc = t & 7;
  int n0 = blockIdx.x * 128;
  int lrow = t >> 1;
  int lkk = (t & 1) * 8;
  float acc[4][5];
#pragma unroll
  for (int i = 0; i < 4; ++i)
#pragma unroll
    for (int j = 0; j < 5; ++j) acc[i][j] = 0.f;

  for (int k0 = 0; k0 < F1; k0 += 16) {
    float av[8];
    int gn = n0 + lrow;
    if (gn < NN) {
      float4 v0 = *(const float4*)(hpre + (size_t)gn * F1 + k0 + lkk);
      float4 v1 = *(const float4*)(hpre + (size_t)gn * F1 + k0 + lkk + 4);
      av[0] = v0.x; av[1] = v0.y; av[2] = v0.z; av[3] = v0.w;
      av[4] = v1.x; av[5] = v1.y; av[6] = v1.z; av[7] = v1.w;
    } else {
#pragma unroll
      for (int j = 0; j < 8; ++j) av[j] = 0.f;
    }
    __syncthreads();
#pragma unroll
    for (int j = 0; j < 8; ++j) {
      int kg = k0 + lkk + j;
      float a = av[j] * sc[kg] + sh[kg];
      a = a > 0.f ? a : (__expf(a) - 1.f);
      Alds[(lkk + j) * 128 + lrow] = a;
    }
    __syncthreads();
#pragma unroll
    for (int k = 0; k < 16; ++k) {
      float4 a4 = *(const float4*)(Alds + k * 128 + tr * 4);
      float aa[4] = {a4.x, a4.y, a4.z, a4.w};
      float w[5];
#pragma unroll
      for (int j = 0; j < 5; ++j) w[j] = Wlds[(k0 + k) * 40 + tc * 5 + j];
#pragma unroll
      for (int i = 0; i < 4; ++i)
#pragma unroll
        for (int j = 0; j < 5; ++j) acc[i][j] = fmaf(aa[i], w[j], acc[i][j]);
    }
  }
#pragma unroll
  for (int i = 0; i < 4; ++i) {
    int gn = n0 + tr * 4 + i;
    if (gn < NN) {
#pragma unroll
      for (int j = 0; j < 5; ++j) h2[(size_t)gn * F2 + tc * 5 + j] = acc[i][j];
    }
  }
}

// ---------------- attention dots layer2 ----------------
__global__ __launch_bounds__(256) void a2_kernel(const float* __restrict__ h2,
                                                 const float* __restrict__ att_src2,
                                                 const float* __restrict__ att_dst2,
                                                 float* __restrict__ a_src2,
                                                 float* __restrict__ a_dst2) {
  __shared__ float ss[40], sd[40];
  int t = threadIdx.x;
  if (t < 40) { ss[t] = att_src2[t]; sd[t] = att_dst2[t]; }
  __syncthreads();
  int n = blockIdx.x * 256 + t;
  if (n >= NN) return;
  const float* row = h2 + (size_t)n * F2;
  float as = 0.f, ad = 0.f;
#pragma unroll
  for (int c = 0; c < 40; ++c) {
    float v = row[c];
    as += v * ss[c];
    ad += v * sd[c];
  }
  a_src2[n] = as;
  a_dst2[n] = ad;
}

// ------- gather layer2: pull aggregation, writes final output -------
// 8 lanes per node; lane l: feats l*5..l*5+4. 32 nodes per block.
__global__ __launch_bounds__(256) void gather2_kernel(const int* __restrict__ rowstart,
                                                      const int* __restrict__ csr_src,
                                                      const float* __restrict__ a_src,
                                                      const float* __restrict__ a_dst,
                                                      const float* __restrict__ h2,
                                                      const float* __restrict__ b2,
                                                      float* __restrict__ out) {
  int t = threadIdx.x;
  int n = blockIdx.x * 32 + (t >> 3);
  if (n >= NN) return;
  int l = t & 7;
  int f0 = l * 5;
  float adst = a_dst[n];
  float acc[5] = {0.f, 0.f, 0.f, 0.f, 0.f};
  float ssum = 0.f;
  int beg = rowstart[n], end = rowstart[n + 1];
  int src = (beg < end) ? csr_src[beg] : 0;
  for (int i = beg; i < end; ++i) {
    int nsrc = (i + 1 < end) ? csr_src[i + 1] : 0;
    float e = a_src[src] + adst;
    e = e > 0.f ? e : 0.2f * e;
    float ex = __expf(e);
    const float* hp = h2 + (size_t)src * F2 + f0;
#pragma unroll
    for (int j = 0; j < 5; ++j) acc[j] = fmaf(ex, hp[j], acc[j]);
    ssum += ex;
    src = nsrc;
  }
  float inv = 1.f / (ssum + 1e-16f);
  float* op = out + (size_t)n * F2 + f0;
#pragma unroll
  for (int j = 0; j < 5; ++j) op[j] = acc[j] * inv + b2[f0 + j];
}

extern "C" void kernel_launch(void* const* d_in, const int* in_sizes, int n_in,
                              void* d_out, int out_size, void* d_ws, size_t ws_size,
                              hipStream_t stream) {
  const float* x        = (const float*)d_in[0];
  const int*   ei       = (const int*)d_in[1];
  const float* W1       = (const float*)d_in[2];
  const float* att_src1 = (const float*)d_in[3];
  const float* att_dst1 = (const float*)d_in[4];
  const float* b1       = (const float*)d_in[5];
  const float* gamma    = (const float*)d_in[6];
  const float* beta     = (const float*)d_in[7];
  const float* W2       = (const float*)d_in[8];
  const float* att_src2 = (const float*)d_in[9];
  const float* att_dst2 = (const float*)d_in[10];
  const float* b2       = (const float*)d_in[11];
  float* out = (float*)d_out;

  // ---- workspace layout ----
  int* deg = (int*)d_ws;                    // 50000 (zeroed)
  float* bnsum = (float*)(deg + NN);        // 128   (zeroed)
  float* bnsq  = bnsum + 128;               // 128   (zeroed)
  int* rowstart = (int*)(bnsq + 128);       // 50001
  int* cursor   = rowstart + (NN + 1);      // 50000
  int* csr_src  = cursor + NN;              // 850000
  float* h1     = (float*)(csr_src + ETOT); // 6.4M  (h2 aliases after gather1)
  float* h2     = h1;                       // 2.0M, alias ok: h1 dead post-gather1
  float* h1b    = h1 + (size_t)NN * F1;     // 6.4M
  float* a_src1 = h1b + (size_t)NN * F1;    // 200000
  float* a_dst1 = a_src1 + NN * 4;          // 200000
  float* a_src2 = a_dst1 + NN * 4;          // 50000
  float* a_dst2 = a_src2 + NN;              // 50000
  float* scale  = a_dst2 + NN;              // 128
  float* shift  = scale + 128;              // 128

  hipMemsetAsync(deg, 0, (NN + 256) * sizeof(int), stream);

  deg_kernel<<<(ETOT + 255) / 256, 256, 0, stream>>>(ei, deg);
  scan_kernel<<<1, 1024, 0, stream>>>(deg, rowstart, cursor);
  fill_kernel<<<(ETOT + 255) / 256, 256, 0, stream>>>(ei, cursor, csr_src);

  gemm1_kernel<<<(NN + 63) / 64, 256, 0, stream>>>(x, W1, h1);
  a1_kernel<<<(NN + 63) / 64, 256, 0, stream>>>(h1, att_src1, att_dst1, a_src1, a_dst1);
  gather1_kernel<<<NN / 8, 256, 0, stream>>>(rowstart, csr_src, a_src1, a_dst1,
                                             h1, b1, h1b, bnsum, bnsq);
  bnstats_kernel<<<1, 128, 0, stream>>>(bnsum, bnsq, gamma, beta, scale, shift);
  gemm2_kernel<<<(NN + 127) / 128, 256, 0, stream>>>(h1b, W2, scale, shift, h2);
  a2_kernel<<<(NN + 255) / 256, 256, 0, stream>>>(h2, att_src2, att_dst2, a_src2, a_dst2);
  gather2_kernel<<<(NN + 31) / 32, 256, 0, stream>>>(rowstart, csr_src, a_src2, a_dst2,
                                                     h2, b2, out);
}

// Round 3
// 580.783 us; speedup vs baseline: 4.0858x; 1.0697x over previous
//
#include <hip/hip_runtime.h>

#define NN 50000
#define EE 800000
#define ETOT 850000
#define FIN 256
#define F1 128
#define F2 40

// ------- GEMM1 + fused attention dots: h1 = x@W1; a_src1/a_dst1 -------
__global__ __launch_bounds__(256) void gemm1_kernel(const float* __restrict__ x,
                                                    const float* __restrict__ W1,
                                                    const float* __restrict__ att_src,
                                                    const float* __restrict__ att_dst,
                                                    float* __restrict__ h1,
                                                    float* __restrict__ a_src,
                                                    float* __restrict__ a_dst) {
  __shared__ float Alds[16 * 68];
  __shared__ float Blds[16 * 128];
  __shared__ float att_s[128], att_d[128];
  const int t = threadIdx.x;
  if (t < 128) { att_s[t] = att_src[t]; att_d[t] = att_dst[t]; }
  const int tx = t & 15;
  const int ty = t >> 4;
  const int m0 = blockIdx.x * 64;
  const int arow = t >> 2;
  const int akk = (t & 3) * 4;
  const int brow = t >> 4;
  const int bc = (t & 15) * 4;

  float acc[4][8];
#pragma unroll
  for (int i = 0; i < 4; ++i)
#pragma unroll
    for (int j = 0; j < 8; ++j) acc[i][j] = 0.f;

  for (int k0 = 0; k0 < FIN; k0 += 16) {
    float4 av = {0.f, 0.f, 0.f, 0.f};
    int gr = m0 + arow;
    if (gr < NN) av = *(const float4*)(x + (size_t)gr * FIN + k0 + akk);
    float4 bv0 = *(const float4*)(W1 + (size_t)(k0 + brow) * F1 + bc);
    float4 bv1 = *(const float4*)(W1 + (size_t)(k0 + brow) * F1 + bc + 64);
    __syncthreads();
    Alds[(akk + 0) * 68 + arow] = av.x;
    Alds[(akk + 1) * 68 + arow] = av.y;
    Alds[(akk + 2) * 68 + arow] = av.z;
    Alds[(akk + 3) * 68 + arow] = av.w;
    *(float4*)(Blds + brow * 128 + bc) = bv0;
    *(float4*)(Blds + brow * 128 + bc + 64) = bv1;
    __syncthreads();
#pragma unroll
    for (int k = 0; k < 16; ++k) {
      float4 a4 = *(const float4*)(Alds + k * 68 + ty * 4);
      float4 b0 = *(const float4*)(Blds + k * 128 + tx * 4);
      float4 b1 = *(const float4*)(Blds + k * 128 + tx * 4 + 64);
      float aa[4] = {a4.x, a4.y, a4.z, a4.w};
      float bb[8] = {b0.x, b0.y, b0.z, b0.w, b1.x, b1.y, b1.z, b1.w};
#pragma unroll
      for (int i = 0; i < 4; ++i)
#pragma unroll
        for (int j = 0; j < 8; ++j) acc[i][j] = fmaf(aa[i], bb[j], acc[i][j]);
    }
  }
#pragma unroll
  for (int i = 0; i < 4; ++i) {
    int gr = m0 + ty * 4 + i;
    if (gr < NN) {
      float4 o0 = {acc[i][0], acc[i][1], acc[i][2], acc[i][3]};
      float4 o1 = {acc[i][4], acc[i][5], acc[i][6], acc[i][7]};
      *(float4*)(h1 + (size_t)gr * F1 + tx * 4) = o0;
      *(float4*)(h1 + (size_t)gr * F1 + tx * 4 + 64) = o1;
    }
  }
  // fused attention dots: reduce over the 8 lanes sharing (row, head-half)
#pragma unroll
  for (int i = 0; i < 4; ++i) {
    float ps = 0.f, pd = 0.f, ps2 = 0.f, pd2 = 0.f;
#pragma unroll
    for (int j = 0; j < 4; ++j) {
      int c = tx * 4 + j;
      ps  += acc[i][j]     * att_s[c];      pd  += acc[i][j]     * att_d[c];
      ps2 += acc[i][j + 4] * att_s[c + 64]; pd2 += acc[i][j + 4] * att_d[c + 64];
    }
#pragma unroll
    for (int off = 1; off < 8; off <<= 1) {
      ps  += __shfl_xor(ps, off);   pd  += __shfl_xor(pd, off);
      ps2 += __shfl_xor(ps2, off);  pd2 += __shfl_xor(pd2, off);
    }
    if ((tx & 7) == 0) {
      int gr = m0 + ty * 4 + i;
      if (gr < NN) {
        int hlo = tx >> 3;  // 0 or 1
        a_src[gr * 4 + hlo]     = ps;
        a_dst[gr * 4 + hlo]     = pd;
        a_src[gr * 4 + 2 + hlo] = ps2;
        a_dst[gr * 4 + 2 + hlo] = pd2;
      }
    }
  }
}

// ---------------- CSR build: degree histogram ----------------
__global__ __launch_bounds__(256) void deg_kernel(const int* __restrict__ ei,
                                                  int* __restrict__ deg) {
  int e = blockIdx.x * 256 + threadIdx.x;
  if (e >= ETOT) return;
  int dst = (e < EE) ? ei[EE + e] : (e - EE);
  atomicAdd(deg + dst, 1);
}

// ------- CSR build: exclusive scan, 2-phase chunk scan (single block) -------
__global__ __launch_bounds__(1024) void scan_kernel(const int* __restrict__ deg,
                                                    int* __restrict__ rowstart,
                                                    int* __restrict__ cursor) {
  __shared__ int part[1024];
  int t = threadIdx.x;
  const int C = (NN + 1023) / 1024;  // 49
  int lo = t * C;
  int hi = lo + C; if (hi > NN) hi = NN;
  int s = 0;
  for (int i = lo; i < hi; ++i) s += deg[i];
  part[t] = s;
  __syncthreads();
  for (int off = 1; off < 1024; off <<= 1) {
    int u = (t >= off) ? part[t - off] : 0;
    __syncthreads();
    part[t] += u;
    __syncthreads();
  }
  int run = part[t] - s;  // exclusive prefix of this chunk
  for (int i = lo; i < hi; ++i) {
    rowstart[i] = run;
    cursor[i] = run;
    run += deg[i];
  }
  if (t == 1023) rowstart[NN] = part[1023];
}

// ---------------- CSR build: scatter fill ----------------
__global__ __launch_bounds__(256) void fill_kernel(const int* __restrict__ ei,
                                                   int* __restrict__ cursor,
                                                   int* __restrict__ csr_src) {
  int e = blockIdx.x * 256 + threadIdx.x;
  if (e >= ETOT) return;
  int src, dst;
  if (e < EE) { src = ei[e]; dst = ei[EE + e]; }
  else        { src = e - EE; dst = src; }
  int pos = atomicAdd(cursor + dst, 1);
  csr_src[pos] = src;
}

// ------- gather layer1: pull aggregation, 4 edges in flight -------
// 32 lanes per node; lane l: head=l>>3, feats l*4..l*4+3. 8 nodes per block.
__global__ __launch_bounds__(256) void gather1_kernel(const int* __restrict__ rowstart,
                                                      const int* __restrict__ csr_src,
                                                      const float* __restrict__ a_src,
                                                      const float* __restrict__ a_dst,
                                                      const float* __restrict__ h1,
                                                      const float* __restrict__ b1,
                                                      float* __restrict__ h1b,
                                                      float* __restrict__ bnsum,
                                                      float* __restrict__ bnsq) {
  __shared__ float bns[128], bnq[128];
  int t = threadIdx.x;
  if (t < 128) { bns[t] = 0.f; bnq[t] = 0.f; }
  __syncthreads();
  int n = blockIdx.x * 8 + (t >> 5);   // grid = NN/8 exactly
  int l = t & 31;
  int head = l >> 3;
  int f0 = l * 4;
  float adst = a_dst[n * 4 + head];
  float acc0 = 0.f, acc1 = 0.f, acc2 = 0.f, acc3 = 0.f, ssum = 0.f;
  int beg = rowstart[n], end = rowstart[n + 1];
  int i = beg;
  for (; i + 3 < end; i += 4) {
    int s0 = csr_src[i + 0];
    int s1 = csr_src[i + 1];
    int s2 = csr_src[i + 2];
    int s3 = csr_src[i + 3];
    float e0 = a_src[s0 * 4 + head] + adst;
    float e1 = a_src[s1 * 4 + head] + adst;
    float e2 = a_src[s2 * 4 + head] + adst;
    float e3 = a_src[s3 * 4 + head] + adst;
    float4 v0 = *(const float4*)(h1 + (size_t)s0 * F1 + f0);
    float4 v1 = *(const float4*)(h1 + (size_t)s1 * F1 + f0);
    float4 v2 = *(const float4*)(h1 + (size_t)s2 * F1 + f0);
    float4 v3 = *(const float4*)(h1 + (size_t)s3 * F1 + f0);
    e0 = e0 > 0.f ? e0 : 0.2f * e0;  float x0 = __expf(e0);
    e1 = e1 > 0.f ? e1 : 0.2f * e1;  float x1 = __expf(e1);
    e2 = e2 > 0.f ? e2 : 0.2f * e2;  float x2 = __expf(e2);
    e3 = e3 > 0.f ? e3 : 0.2f * e3;  float x3 = __expf(e3);
    acc0 = fmaf(x0, v0.x, fmaf(x1, v1.x, fmaf(x2, v2.x, fmaf(x3, v3.x, acc0))));
    acc1 = fmaf(x0, v0.y, fmaf(x1, v1.y, fmaf(x2, v2.y, fmaf(x3, v3.y, acc1))));
    acc2 = fmaf(x0, v0.z, fmaf(x1, v1.z, fmaf(x2, v2.z, fmaf(x3, v3.z, acc2))));
    acc3 = fmaf(x0, v0.w, fmaf(x1, v1.w, fmaf(x2, v2.w, fmaf(x3, v3.w, acc3))));
    ssum += x0 + x1 + x2 + x3;
  }
  for (; i < end; ++i) {
    int s0 = csr_src[i];
    float e0 = a_src[s0 * 4 + head] + adst;
    e0 = e0 > 0.f ? e0 : 0.2f * e0;
    float x0 = __expf(e0);
    float4 v0 = *(const float4*)(h1 + (size_t)s0 * F1 + f0);
    acc0 = fmaf(x0, v0.x, acc0);
    acc1 = fmaf(x0, v0.y, acc1);
    acc2 = fmaf(x0, v0.z, acc2);
    acc3 = fmaf(x0, v0.w, acc3);
    ssum += x0;
  }
  float inv = 1.f / (ssum + 1e-16f);
  float4 bb = *(const float4*)(b1 + f0);
  float4 o;
  o.x = acc0 * inv + bb.x;
  o.y = acc1 * inv + bb.y;
  o.z = acc2 * inv + bb.z;
  o.w = acc3 * inv + bb.w;
  *(float4*)(h1b + (size_t)n * F1 + f0) = o;
  atomicAdd(&bns[f0 + 0], o.x); atomicAdd(&bnq[f0 + 0], o.x * o.x);
  atomicAdd(&bns[f0 + 1], o.y); atomicAdd(&bnq[f0 + 1], o.y * o.y);
  atomicAdd(&bns[f0 + 2], o.z); atomicAdd(&bnq[f0 + 2], o.z * o.z);
  atomicAdd(&bns[f0 + 3], o.w); atomicAdd(&bnq[f0 + 3], o.w * o.w);
  __syncthreads();
  if (t < 128) {
    atomicAdd(bnsum + t, bns[t]);
    atomicAdd(bnsq + t, bnq[t]);
  }
}

// ---------------- BN stats -> per-feature scale/shift ----------------
__global__ void bnstats_kernel(const float* __restrict__ bnsum, const float* __restrict__ bnsq,
                               const float* __restrict__ gamma, const float* __restrict__ beta,
                               float* __restrict__ scale, float* __restrict__ shift) {
  int f = threadIdx.x;
  if (f < 128) {
    const float invN = 1.f / (float)NN;
    float mu = bnsum[f] * invN;
    float var = bnsq[f] * invN - mu * mu;
    float sc = gamma[f] * rsqrtf(var + 1e-5f);
    scale[f] = sc;
    shift[f] = beta[f] - mu * sc;
  }
}

// -- GEMM2 (BN+ELU fused on A-load, a2 dots fused in epilogue) --
__global__ __launch_bounds__(256) void gemm2_kernel(const float* __restrict__ hpre,
                                                    const float* __restrict__ W2,
                                                    const float* __restrict__ scale,
                                                    const float* __restrict__ shift,
                                                    const float* __restrict__ att_src2,
                                                    const float* __restrict__ att_dst2,
                                                    float* __restrict__ h2,
                                                    float* __restrict__ a_src2,
                                                    float* __restrict__ a_dst2) {
  __shared__ float Wlds[128 * 40];
  __shared__ float Alds[16 * 128];
  __shared__ float sc[128], sh[128];
  int t = threadIdx.x;
  for (int i = t; i < 128 * 40; i += 256) Wlds[i] = W2[i];
  if (t < 128) { sc[t] = scale[t]; sh[t] = shift[t]; }
  int tr = t >> 3;
  int tc = t & 7;
  float as5[5], ad5[5];
#pragma unroll
  for (int j = 0; j < 5; ++j) { as5[j] = att_src2[tc * 5 + j]; ad5[j] = att_dst2[tc * 5 + j]; }
  int n0 = blockIdx.x * 128;
  int lrow = t >> 1;
  int lkk = (t & 1) * 8;
  float acc[4][5];
#pragma unroll
  for (int i = 0; i < 4; ++i)
#pragma unroll
    for (int j = 0; j < 5; ++j) acc[i][j] = 0.f;

  for (int k0 = 0; k0 < F1; k0 += 16) {
    float av[8];
    int gn = n0 + lrow;
    if (gn < NN) {
      float4 v0 = *(const float4*)(hpre + (size_t)gn * F1 + k0 + lkk);
      float4 v1 = *(const float4*)(hpre + (size_t)gn * F1 + k0 + lkk + 4);
      av[0] = v0.x; av[1] = v0.y; av[2] = v0.z; av[3] = v0.w;
      av[4] = v1.x; av[5] = v1.y; av[6] = v1.z; av[7] = v1.w;
    } else {
#pragma unroll
      for (int j = 0; j < 8; ++j) av[j] = 0.f;
    }
    __syncthreads();
#pragma unroll
    for (int j = 0; j < 8; ++j) {
      int kg = k0 + lkk + j;
      float a = av[j] * sc[kg] + sh[kg];
      a = a > 0.f ? a : (__expf(a) - 1.f);
      Alds[(lkk + j) * 128 + lrow] = a;
    }
    __syncthreads();
#pragma unroll
    for (int k = 0; k < 16; ++k) {
      float4 a4 = *(const float4*)(Alds + k * 128 + tr * 4);
      float aa[4] = {a4.x, a4.y, a4.z, a4.w};
      float w[5];
#pragma unroll
      for (int j = 0; j < 5; ++j) w[j] = Wlds[(k0 + k) * 40 + tc * 5 + j];
#pragma unroll
      for (int i = 0; i < 4; ++i)
#pragma unroll
        for (int j = 0; j < 5; ++j) acc[i][j] = fmaf(aa[i], w[j], acc[i][j]);
    }
  }
#pragma unroll
  for (int i = 0; i < 4; ++i) {
    int gn = n0 + tr * 4 + i;
    if (gn < NN) {
#pragma unroll
      for (int j = 0; j < 5; ++j) h2[(size_t)gn * F2 + tc * 5 + j] = acc[i][j];
    }
  }
  // fused a2 dots: reduce across the 8 lanes (tc) sharing a row
#pragma unroll
  for (int i = 0; i < 4; ++i) {
    float ps = 0.f, pd = 0.f;
#pragma unroll
    for (int j = 0; j < 5; ++j) { ps += acc[i][j] * as5[j]; pd += acc[i][j] * ad5[j]; }
#pragma unroll
    for (int off = 1; off < 8; off <<= 1) {
      ps += __shfl_xor(ps, off);
      pd += __shfl_xor(pd, off);
    }
    if (tc == 0) {
      int gn = n0 + tr * 4 + i;
      if (gn < NN) { a_src2[gn] = ps; a_dst2[gn] = pd; }
    }
  }
}

// ------- gather layer2: pull aggregation, 4 edges in flight, writes output -------
// 8 lanes per node; lane l: feats l*5..l*5+4. 32 nodes per block.
__global__ __launch_bounds__(256) void gather2_kernel(const int* __restrict__ rowstart,
                                                      const int* __restrict__ csr_src,
                                                      const float* __restrict__ a_src,
                                                      const float* __restrict__ a_dst,
                                                      const float* __restrict__ h2,
                                                      const float* __restrict__ b2,
                                                      float* __restrict__ out) {
  int t = threadIdx.x;
  int n = blockIdx.x * 32 + (t >> 3);
  if (n >= NN) return;
  int l = t & 7;
  int f0 = l * 5;
  float adst = a_dst[n];
  float acc[5] = {0.f, 0.f, 0.f, 0.f, 0.f};
  float ssum = 0.f;
  int beg = rowstart[n], end = rowstart[n + 1];
  int i = beg;
  for (; i + 3 < end; i += 4) {
    int s0 = csr_src[i + 0];
    int s1 = csr_src[i + 1];
    int s2 = csr_src[i + 2];
    int s3 = csr_src[i + 3];
    float e0 = a_src[s0] + adst;
    float e1 = a_src[s1] + adst;
    float e2 = a_src[s2] + adst;
    float e3 = a_src[s3] + adst;
    const float* p0 = h2 + (size_t)s0 * F2 + f0;
    const float* p1 = h2 + (size_t)s1 * F2 + f0;
    const float* p2 = h2 + (size_t)s2 * F2 + f0;
    const float* p3 = h2 + (size_t)s3 * F2 + f0;
    e0 = e0 > 0.f ? e0 : 0.2f * e0;  float x0 = __expf(e0);
    e1 = e1 > 0.f ? e1 : 0.2f * e1;  float x1 = __expf(e1);
    e2 = e2 > 0.f ? e2 : 0.2f * e2;  float x2 = __expf(e2);
    e3 = e3 > 0.f ? e3 : 0.2f * e3;  float x3 = __expf(e3);
#pragma unroll
    for (int j = 0; j < 5; ++j)
      acc[j] = fmaf(x0, p0[j], fmaf(x1, p1[j], fmaf(x2, p2[j], fmaf(x3, p3[j], acc[j]))));
    ssum += x0 + x1 + x2 + x3;
  }
  for (; i < end; ++i) {
    int s0 = csr_src[i];
    float e0 = a_src[s0] + adst;
    e0 = e0 > 0.f ? e0 : 0.2f * e0;
    float x0 = __expf(e0);
    const float* p0 = h2 + (size_t)s0 * F2 + f0;
#pragma unroll
    for (int j = 0; j < 5; ++j) acc[j] = fmaf(x0, p0[j], acc[j]);
    ssum += x0;
  }
  float inv = 1.f / (ssum + 1e-16f);
  float* op = out + (size_t)n * F2 + f0;
#pragma unroll
  for (int j = 0; j < 5; ++j) op[j] = acc[j] * inv + b2[f0 + j];
}

extern "C" void kernel_launch(void* const* d_in, const int* in_sizes, int n_in,
                              void* d_out, int out_size, void* d_ws, size_t ws_size,
                              hipStream_t stream) {
  const float* x        = (const float*)d_in[0];
  const int*   ei       = (const int*)d_in[1];
  const float* W1       = (const float*)d_in[2];
  const float* att_src1 = (const float*)d_in[3];
  const float* att_dst1 = (const float*)d_in[4];
  const float* b1       = (const float*)d_in[5];
  const float* gamma    = (const float*)d_in[6];
  const float* beta     = (const float*)d_in[7];
  const float* W2       = (const float*)d_in[8];
  const float* att_src2 = (const float*)d_in[9];
  const float* att_dst2 = (const float*)d_in[10];
  const float* b2       = (const float*)d_in[11];
  float* out = (float*)d_out;

  // ---- workspace layout ----
  int* deg = (int*)d_ws;                    // 50000 (zeroed)
  float* bnsum = (float*)(deg + NN);        // 128   (zeroed)
  float* bnsq  = bnsum + 128;               // 128   (zeroed)
  int* rowstart = (int*)(bnsq + 128);       // 50001
  int* cursor   = rowstart + (NN + 1);      // 50000
  int* csr_src  = cursor + NN;              // 850000
  float* h1     = (float*)(csr_src + ETOT); // 6.4M  (h2 aliases after gather1)
  float* h2     = h1;                       // 2.0M, alias ok: h1 dead post-gather1
  float* h1b    = h1 + (size_t)NN * F1;     // 6.4M
  float* a_src1 = h1b + (size_t)NN * F1;    // 200000
  float* a_dst1 = a_src1 + NN * 4;          // 200000
  float* a_src2 = a_dst1 + NN * 4;          // 50000
  float* a_dst2 = a_src2 + NN;              // 50000
  float* scale  = a_dst2 + NN;              // 128
  float* shift  = scale + 128;              // 128

  hipMemsetAsync(deg, 0, (NN + 256) * sizeof(int), stream);

  deg_kernel<<<(ETOT + 255) / 256, 256, 0, stream>>>(ei, deg);
  scan_kernel<<<1, 1024, 0, stream>>>(deg, rowstart, cursor);
  fill_kernel<<<(ETOT + 255) / 256, 256, 0, stream>>>(ei, cursor, csr_src);

  gemm1_kernel<<<(NN + 63) / 64, 256, 0, stream>>>(x, W1, att_src1, att_dst1,
                                                   h1, a_src1, a_dst1);
  gather1_kernel<<<NN / 8, 256, 0, stream>>>(rowstart, csr_src, a_src1, a_dst1,
                                             h1, b1, h1b, bnsum, bnsq);
  bnstats_kernel<<<1, 128, 0, stream>>>(bnsum, bnsq, gamma, beta, scale, shift);
  gemm2_kernel<<<(NN + 127) / 128, 256, 0, stream>>>(h1b, W2, scale, shift,
                                                     att_src2, att_dst2,
                                                     h2, a_src2, a_dst2);
  gather2_kernel<<<(NN + 31) / 32, 256, 0, stream>>>(rowstart, csr_src, a_src2, a_dst2,
                                                     h2, b2, out);
}